// Round 12
// baseline (193.085 us; speedup 1.0000x reference)
//
#include <hip/hip_runtime.h>
#include <hip/hip_bf16.h>
#include <math.h>

#define NB 8
#define NN 8192
#define ND 1024
#define NH 256
#define NC 2
#define M_ALL (NB * NN)   // 65536 rows
#define BM 256            // block tile rows
#define BK 64             // K per iteration (2 MFMA k-steps)
#define NT (ND / BK)      // 16 iterations
#define PSTRIDE 260       // per-tile partial: 256 pooled + m_t + l_t (+pad)

typedef __attribute__((ext_vector_type(8))) short bf16x8;
typedef __attribute__((ext_vector_type(4))) float f32x4;

// barrier WITHOUT the compiler's vmcnt(0) drain: LDS ordering only.
#define BARRIER_LGKM() asm volatile("s_waitcnt lgkmcnt(0)\n\ts_barrier" ::: "memory")

__device__ inline unsigned short f2bf(float f) {   // RNE float -> bf16 bits
    unsigned int u = __builtin_bit_cast(unsigned int, f);
    u += 0x7FFFu + ((u >> 16) & 1u);
    return (unsigned short)(u >> 16);
}
__device__ inline float bf2f(unsigned short s) {
    unsigned int u = ((unsigned int)s) << 16;
    return __builtin_bit_cast(float, u);
}
__device__ inline unsigned int pk_bf16(float a, float b) {  // low=a, high=b
    __hip_bfloat162 t = __float22bfloat162_rn(float2{a, b});
    unsigned int r;
    __builtin_memcpy(&r, &t, 4);
    return r;
}

__device__ inline float wave_reduce_sum(float v) {
#pragma unroll
    for (int off = 32; off > 0; off >>= 1) v += __shfl_down(v, off, 64);
    return v;
}
__device__ inline float wave_reduce_max(float v) {
#pragma unroll
    for (int off = 32; off > 0; off >>= 1) v = fmaxf(v, __shfl_down(v, off, 64));
    return v;
}

// ---------------------------------------------------------------------------
// Pack Wp into bf16 hi/lo, MFMA-B-fragment-contiguous:
// frag (t = kstep 0..31, f = col-frag 0..15), lane l holds
// B[k = t*32 + (l>>4)*8 + j][col = f*16 + (l&15)], j=0..7 contiguous.
// ---------------------------------------------------------------------------
__global__ void pack_kernel(const float* __restrict__ Wp,
                            unsigned short* __restrict__ hi,
                            unsigned short* __restrict__ lo)
{
    int idx  = blockIdx.x * 256 + threadIdx.x;   // 0..32767
    int lane = idx & 63;
    int f    = (idx >> 6) & 15;
    int t    = idx >> 10;
    int col  = f * 16 + (lane & 15);
    int k0   = t * 32 + (lane >> 4) * 8;
    size_t off = (size_t)idx * 8;
#pragma unroll
    for (int j = 0; j < 8; ++j) {
        float w = Wp[(size_t)(k0 + j) * NH + col];
        unsigned short h = f2bf(w);
        hi[off + j] = h;
        lo[off + j] = f2bf(w - bf2f(h));
    }
}

// ---------------------------------------------------------------------------
// Fused GEMM + SiLU + attention logit + flash-style tile pooling.
// 256x256 tile, 8 waves (2 row x 4 col groups), BK=64 (2 k-steps/iter,
// 16 iters): per-iteration fixed costs (B-L2 latency at the lockstep
// barrier, barrier skew, dswrite) amortize over 2x MFMA vs BK=32.
// vmcnt-FIFO order per iter: [all 16 B frags] -> [x(t+2) 8 loads] ->
// MFMA kstep0 (B0 wait leaves B1+x) -> MFMA kstep1 (B1 wait leaves x)
// -> dswrite x(t+1) -> lgkm-only barrier. x depth-2 reg pipeline.
// Epilogue: h stays fp32 in acc; per-tile (m_t, l_t, pooled partial).
// ---------------------------------------------------------------------------
__global__ __launch_bounds__(512, 2)
void gemm_kernel(const float* __restrict__ x,
                 const unsigned short* __restrict__ Bhi,
                 const unsigned short* __restrict__ Blo,
                 const float* __restrict__ bp,
                 const float* __restrict__ Wa,
                 const float* __restrict__ ba,
                 const int* __restrict__ lengths,
                 float* __restrict__ part)
{
    __shared__ __align__(16) unsigned char lds_raw[65536];  // A dbuf 2x32KB; reused in epilogue

    const int tid  = threadIdx.x;
    const int wave = tid >> 6;
    const int lane = tid & 63;
    const int wr = wave >> 2;           // 0..1: 128-row group
    const int wc = wave & 3;            // 0..3: 64-col group
    const int blk = blockIdx.x;
    const size_t row0 = (size_t)blk * BM;

    // ragged early-exit: this block's rows all beyond bag length
    const int bag   = blk >> 5;                // 32 blocks per bag
    const int lrow0 = (blk & 31) * BM;         // bag-local first row
    const int len   = lengths[bag];
    if (lrow0 >= len) return;

    // ---- x staging: thread -> row (tid>>1), 32-float half (tid&1)
    const int srow = tid >> 1;                 // 0..255
    const int shalf = tid & 1;
    const float* xp = x + (row0 + srow) * ND + shalf * 32;
    const int swz = (srow & 7) << 4;
    int woff[4];
#pragma unroll
    for (int q = 0; q < 4; ++q) woff[q] = (shalf * 64 + q * 16) ^ swz;
    char* const wrow = (char*)lds_raw + srow * 128;

    float4 gE[8], gO[8];                       // x reg sets (even/odd tiles)
    auto issueX = [&](int t, float4* g) {
        const float4* p = (const float4*)(xp + (size_t)t * BK);
#pragma unroll
        for (int i = 0; i < 8; ++i) g[i] = p[i];
    };
    auto dswrite = [&](int buf, const float4* g) {
        char* base = wrow + buf * 32768;
#pragma unroll
        for (int q = 0; q < 4; ++q) {
            uint4 w;
            w.x = pk_bf16(g[2 * q].x,     g[2 * q].y);
            w.y = pk_bf16(g[2 * q].z,     g[2 * q].w);
            w.z = pk_bf16(g[2 * q + 1].x, g[2 * q + 1].y);
            w.w = pk_bf16(g[2 * q + 1].z, g[2 * q + 1].w);
            *(uint4*)(base + woff[q]) = w;
        }
    };

    // ---- B fragment bases (frag idx = kstep*16 + wc*4 + n; 512 ushorts/frag)
    const unsigned short* bhp = Bhi + ((size_t)(wc * 4) * 64 + lane) * 8;
    const unsigned short* blp = Blo + ((size_t)(wc * 4) * 64 + lane) * 8;

    // ---- A fragment addressing
    const int arow_l = lane & 15;
    const int akg    = (lane >> 4) * 16;       // 16-B k-group offset

    f32x4 acc[8][4];
#pragma unroll
    for (int m = 0; m < 8; ++m)
#pragma unroll
        for (int n = 0; n < 4; ++n) acc[m][n] = f32x4{0.f, 0.f, 0.f, 0.f};

    auto body = [&](int t, float4* cons, float4* iss) {
        // 1) ALL B loads first (B0 then B1; their waits leave younger x alive)
        const unsigned short* bh0 = bhp + (size_t)(2 * t)     * 8192;
        const unsigned short* bl0 = blp + (size_t)(2 * t)     * 8192;
        const unsigned short* bh1 = bhp + (size_t)(2 * t + 1) * 8192;
        const unsigned short* bl1 = blp + (size_t)(2 * t + 1) * 8192;
        bf16x8 b0h[4], b0l[4], b1h[4], b1l[4];
#pragma unroll
        for (int n = 0; n < 4; ++n) {
            b0h[n] = *(const bf16x8*)(bh0 + n * 512);
            b0l[n] = *(const bf16x8*)(bl0 + n * 512);
        }
#pragma unroll
        for (int n = 0; n < 4; ++n) {
            b1h[n] = *(const bf16x8*)(bh1 + n * 512);
            b1l[n] = *(const bf16x8*)(bl1 + n * 512);
        }
        // 2) x prefetch for t+2 (newest vmem -> survives all B waits)
        if (t + 2 < NT) issueX(t + 2, iss);
        // 3) two MFMA k-step phases from LDS buf t&1
        const char* ab = (const char*)lds_raw + (t & 1) * 32768;
        __builtin_amdgcn_s_setprio(1);
#pragma unroll
        for (int kk = 0; kk < 2; ++kk) {
            const bf16x8* BH = kk ? b1h : b0h;
            const bf16x8* BL = kk ? b1l : b0l;
#pragma unroll
            for (int mm = 0; mm < 2; ++mm) {
                bf16x8 af[4];
#pragma unroll
                for (int q = 0; q < 4; ++q) {
                    const int arow = wr * 128 + (mm * 4 + q) * 16 + arow_l;
                    af[q] = *(const bf16x8*)(ab + arow * 128 + ((kk * 64 + akg) ^ ((arow & 7) << 4)));
                }
#pragma unroll
                for (int n = 0; n < 4; ++n)
#pragma unroll
                    for (int q = 0; q < 4; ++q)
                        acc[mm * 4 + q][n] = __builtin_amdgcn_mfma_f32_16x16x32_bf16(af[q], BH[n], acc[mm * 4 + q][n], 0, 0, 0);
#pragma unroll
                for (int n = 0; n < 4; ++n)
#pragma unroll
                    for (int q = 0; q < 4; ++q)
                        acc[mm * 4 + q][n] = __builtin_amdgcn_mfma_f32_16x16x32_bf16(af[q], BL[n], acc[mm * 4 + q][n], 0, 0, 0);
            }
        }
        __builtin_amdgcn_s_setprio(0);
        // 4) stage x tile t+1 into the other buffer (loads complete by now)
        if (t < NT - 1) {
            dswrite((t + 1) & 1, cons);
            BARRIER_LGKM();
        }
    };

    // prologue: x(0) -> LDS buf0; x(1) -> odd set (in flight across barrier)
    issueX(0, gE);
    dswrite(0, gE);
    issueX(1, gO);
    BARRIER_LGKM();

    // iter t even: consumes odd set (x(t+1)), issues even set (x(t+2))
    for (int tt = 0; tt < NT; tt += 2) {
        body(tt,     gO, gE);
        body(tt + 1, gE, gO);
    }

    // =========== epilogue: SiLU in-register, logits, flash-pool ===========
    float* a_red  = (float*)lds_raw;            // [4][256]  4 KB
    float* a_vals = (float*)(lds_raw + 4096);   // [256]     1 KB
    float* redm   = (float*)(lds_raw + 5120);   // [8]
    float* bc2    = (float*)(lds_raw + 5152);   // [2]
    float* pp     = (float*)(lds_raw + 5248);   // [2][256]  2 KB

    const int rg = lane >> 4;
    float bpc[4], wac[4];
#pragma unroll
    for (int n = 0; n < 4; ++n) {
        int col = wc * 64 + n * 16 + (lane & 15);
        bpc[n] = bp[col];
        wac[n] = Wa[col];
    }

    // SiLU (overwrite acc with h, fp32) + per-row attention-logit partials
    float pa[32];
#pragma unroll
    for (int i = 0; i < 32; ++i) pa[i] = 0.f;
#pragma unroll
    for (int m = 0; m < 8; ++m)
#pragma unroll
        for (int n = 0; n < 4; ++n)
#pragma unroll
            for (int j = 0; j < 4; ++j) {
                float v  = acc[m][n][j] + bpc[n];
                float hh = v / (1.f + __expf(-v));
                acc[m][n][j] = hh;
                pa[m * 4 + j] = fmaf(hh, wac[n], pa[m * 4 + j]);
            }
    // reduce pa over the 16 lanes sharing each row
#pragma unroll
    for (int i = 0; i < 32; ++i) {
#pragma unroll
        for (int off = 1; off < 16; off <<= 1)
            pa[i] += __shfl_xor(pa[i], off, 64);
    }
    __syncthreads();          // K-loop LDS reads done before overlay writes
    if ((lane & 15) == 0) {
#pragma unroll
        for (int m = 0; m < 8; ++m)
#pragma unroll
            for (int j = 0; j < 4; ++j)
                a_red[wc * BM + wr * 128 + m * 16 + rg * 4 + j] = pa[m * 4 + j];
    }
    __syncthreads();
    if (tid < BM) {
        float av = a_red[tid] + a_red[BM + tid] + a_red[2 * BM + tid] + a_red[3 * BM + tid] + ba[0];
        a_vals[tid] = (lrow0 + tid < len) ? av : -3e38f;   // mask invalid rows
    }
    __syncthreads();

    // m_t = max over valid rows
    float mv = (tid < BM) ? a_vals[tid] : -3e38f;
    mv = wave_reduce_max(mv);
    if (lane == 0) redm[wave] = mv;
    __syncthreads();
    if (tid == 0) {
        float m = redm[0];
#pragma unroll
        for (int w = 1; w < 8; ++w) m = fmaxf(m, redm[w]);
        bc2[0] = m;
    }
    __syncthreads();
    const float m_t = bc2[0];

    // l_t = sum exp(a - m_t) over valid rows
    float es = (tid < BM) ? __expf(a_vals[tid] - m_t) : 0.f;
    es = wave_reduce_sum(es);
    if (lane == 0) redm[wave] = es;
    __syncthreads();
    float l_t = 0.f;
    if (tid == 0) {
#pragma unroll
        for (int w = 0; w < 8; ++w) l_t += redm[w];
    }

    // pooled partial: pp[c] = sum_rows exp(a-m_t) * h[row][c]  (h fp32 in acc)
    float ev[32];
    const int rbase = wr * 128 + rg * 4;
#pragma unroll
    for (int m = 0; m < 8; ++m)
#pragma unroll
        for (int j = 0; j < 4; ++j)
            ev[m * 4 + j] = __expf(a_vals[rbase + m * 16 + j] - m_t);
#pragma unroll
    for (int n = 0; n < 4; ++n) {
        float s = 0.f;
#pragma unroll
        for (int m = 0; m < 8; ++m)
#pragma unroll
            for (int j = 0; j < 4; ++j)
                s = fmaf(ev[m * 4 + j], acc[m][n][j], s);
        s += __shfl_xor(s, 16, 64);
        s += __shfl_xor(s, 32, 64);
        if (lane < 16) pp[wr * 256 + wc * 64 + n * 16 + lane] = s;
    }
    __syncthreads();

    const size_t pbase = ((size_t)bag * 32 + (blk & 31)) * PSTRIDE;
    if (tid < BM) part[pbase + tid] = pp[tid] + pp[256 + tid];
    if (tid == 0) { part[pbase + 256] = m_t; part[pbase + 257] = l_t; }
}

// ---------------------------------------------------------------------------
// final: one block per bag. Flash-combine the per-tile partials, then
// logits = pooled @ Wc + bc.
// ---------------------------------------------------------------------------
__global__ __launch_bounds__(256)
void final_kernel(const float* __restrict__ part, const int* __restrict__ lengths,
                  const float* __restrict__ Wc, const float* __restrict__ bc,
                  float* __restrict__ out)
{
    __shared__ float red0[4], red1[4];
    const int b = blockIdx.x;
    const int c = threadIdx.x;
    const int len = lengths[b];
    int nt = (len + BM - 1) / BM;
    if (nt > 32) nt = 32;

    float mg = -3e38f;
    for (int t = 0; t < nt; ++t)
        mg = fmaxf(mg, part[((size_t)b * 32 + t) * PSTRIDE + 256]);

    float W = 0.f, pooled = 0.f;
    for (int t = 0; t < nt; ++t) {
        const size_t pb = ((size_t)b * 32 + t) * PSTRIDE;
        float sc = __expf(part[pb + 256] - mg);
        W      = fmaf(sc, part[pb + 257], W);
        pooled = fmaf(sc, part[pb + c],  pooled);
    }
    pooled /= W;

    const float wc0 = Wc[c * NC + 0], wc1 = Wc[c * NC + 1];
    const int wave = threadIdx.x >> 6, lane = threadIdx.x & 63;
    float l0 = wave_reduce_sum(pooled * wc0);
    float l1 = wave_reduce_sum(pooled * wc1);
    if (lane == 0) { red0[wave] = l0; red1[wave] = l1; }
    __syncthreads();
    if (threadIdx.x == 0) {
        out[b * NC + 0] = red0[0] + red0[1] + red0[2] + red0[3] + bc[0];
        out[b * NC + 1] = red1[0] + red1[1] + red1[2] + red1[3] + bc[1];
    }
}

extern "C" void kernel_launch(void* const* d_in, const int* in_sizes, int n_in,
                              void* d_out, int out_size, void* d_ws, size_t ws_size,
                              hipStream_t stream)
{
    const float* x       = (const float*)d_in[0];
    const int*   lengths = (const int*)d_in[1];
    const float* Wp      = (const float*)d_in[2];
    const float* bp      = (const float*)d_in[3];
    const float* Wa      = (const float*)d_in[4];
    const float* ba      = (const float*)d_in[5];
    const float* Wc      = (const float*)d_in[6];
    const float* bc      = (const float*)d_in[7];
    float* out = (float*)d_out;

    // workspace layout
    unsigned short* whi = (unsigned short*)d_ws;              // 512 KB
    unsigned short* wlo = whi + 262144;                       // 512 KB
    float* part = (float*)(wlo + 262144);                     // 8*32*260 f = 260 KB

    pack_kernel<<<128, 256, 0, stream>>>(Wp, whi, wlo);
    gemm_kernel<<<M_ALL / BM, 512, 0, stream>>>(x, whi, wlo, bp, Wa, ba, lengths, part);
    final_kernel<<<NB, 256, 0, stream>>>(part, lengths, Wc, bc, out);
}

// Round 13
// 95.468 us; speedup vs baseline: 2.0225x; 2.0225x over previous
//
#include <hip/hip_runtime.h>
#include <hip/hip_bf16.h>
#include <math.h>

#define NB 8
#define NN 8192
#define ND 1024
#define NH 256
#define NC 2
#define M_ALL (NB * NN)   // 65536 rows
#define BM 256            // block tile rows
#define BK 64             // K per iteration (2 MFMA k-steps)
#define NT (ND / BK)      // 16 iterations
#define PSTRIDE 260       // per-tile partial: 256 pooled + m_t + l_t (+pad)

typedef __attribute__((ext_vector_type(8))) short bf16x8;
typedef __attribute__((ext_vector_type(4))) float f32x4;

// barrier WITHOUT the compiler's vmcnt(0) drain: LDS ordering only.
#define BARRIER_LGKM() asm volatile("s_waitcnt lgkmcnt(0)\n\ts_barrier" ::: "memory")

__device__ inline unsigned short f2bf(float f) {   // RNE float -> bf16 bits
    unsigned int u = __builtin_bit_cast(unsigned int, f);
    u += 0x7FFFu + ((u >> 16) & 1u);
    return (unsigned short)(u >> 16);
}
__device__ inline float bf2f(unsigned short s) {
    unsigned int u = ((unsigned int)s) << 16;
    return __builtin_bit_cast(float, u);
}
__device__ inline unsigned int pk_bf16(float a, float b) {  // low=a, high=b
    __hip_bfloat162 t = __float22bfloat162_rn(float2{a, b});
    unsigned int r;
    __builtin_memcpy(&r, &t, 4);
    return r;
}

__device__ inline float wave_reduce_sum(float v) {
#pragma unroll
    for (int off = 32; off > 0; off >>= 1) v += __shfl_down(v, off, 64);
    return v;
}
__device__ inline float wave_reduce_max(float v) {
#pragma unroll
    for (int off = 32; off > 0; off >>= 1) v = fmaxf(v, __shfl_down(v, off, 64));
    return v;
}

// ---------------------------------------------------------------------------
// Pack Wp into bf16 hi/lo, MFMA-B-fragment-contiguous:
// frag (t = kstep 0..31, f = col-frag 0..15), lane l holds
// B[k = t*32 + (l>>4)*8 + j][col = f*16 + (l&15)], j=0..7 contiguous.
// ---------------------------------------------------------------------------
__global__ void pack_kernel(const float* __restrict__ Wp,
                            unsigned short* __restrict__ hi,
                            unsigned short* __restrict__ lo)
{
    int idx  = blockIdx.x * 256 + threadIdx.x;   // 0..32767
    int lane = idx & 63;
    int f    = (idx >> 6) & 15;
    int t    = idx >> 10;
    int col  = f * 16 + (lane & 15);
    int k0   = t * 32 + (lane >> 4) * 8;
    size_t off = (size_t)idx * 8;
#pragma unroll
    for (int j = 0; j < 8; ++j) {
        float w = Wp[(size_t)(k0 + j) * NH + col];
        unsigned short h = f2bf(w);
        hi[off + j] = h;
        lo[off + j] = f2bf(w - bf2f(h));
    }
}

// ---------------------------------------------------------------------------
// Fused GEMM + SiLU + attention logit + flash-style tile pooling.
// 256x256 tile, 8 waves (2 row x 4 col groups), BK=64 (2 k-steps/iter,
// 16 iters): per-iteration fixed costs amortize over 2x MFMA vs BK=32.
// REGISTER-DISCIPLINED vs round 12 (which spilled 192MB to scratch):
//  - single x landing set gx[8] (32 VGPR), 1-iter lifetime (~5000 cyc)
//  - one B reg set (32 VGPR), loaded per k-step sequentially
// Non-acc VGPR ~100 < 128, acc 128 AGPR -> no spills at 2 waves/SIMD.
// Epilogue: h stays fp32 in acc; per-tile (m_t, l_t, pooled partial).
// ---------------------------------------------------------------------------
__global__ __launch_bounds__(512, 2)
void gemm_kernel(const float* __restrict__ x,
                 const unsigned short* __restrict__ Bhi,
                 const unsigned short* __restrict__ Blo,
                 const float* __restrict__ bp,
                 const float* __restrict__ Wa,
                 const float* __restrict__ ba,
                 const int* __restrict__ lengths,
                 float* __restrict__ part)
{
    __shared__ __align__(16) unsigned char lds_raw[65536];  // A dbuf 2x32KB; reused in epilogue

    const int tid  = threadIdx.x;
    const int wave = tid >> 6;
    const int lane = tid & 63;
    const int wr = wave >> 2;           // 0..1: 128-row group
    const int wc = wave & 3;            // 0..3: 64-col group
    const int blk = blockIdx.x;
    const size_t row0 = (size_t)blk * BM;

    // ragged early-exit: this block's rows all beyond bag length
    const int bag   = blk >> 5;                // 32 blocks per bag
    const int lrow0 = (blk & 31) * BM;         // bag-local first row
    const int len   = lengths[bag];
    if (lrow0 >= len) return;

    // ---- x staging: thread -> row (tid>>1), 32-float half (tid&1)
    const int srow = tid >> 1;                 // 0..255
    const int shalf = tid & 1;
    const float* xp = x + (row0 + srow) * ND + shalf * 32;
    const int swz = (srow & 7) << 4;
    int woff[4];
#pragma unroll
    for (int q = 0; q < 4; ++q) woff[q] = (shalf * 64 + q * 16) ^ swz;
    char* const wrow = (char*)lds_raw + srow * 128;

    float4 gx[8];                              // single landing set (32 VGPR)
    auto issueX = [&](int t) {
        const float4* p = (const float4*)(xp + (size_t)t * BK);
#pragma unroll
        for (int i = 0; i < 8; ++i) gx[i] = p[i];
    };
    auto dswrite = [&](int buf) {
        char* base = wrow + buf * 32768;
#pragma unroll
        for (int q = 0; q < 4; ++q) {
            uint4 w;
            w.x = pk_bf16(gx[2 * q].x,     gx[2 * q].y);
            w.y = pk_bf16(gx[2 * q].z,     gx[2 * q].w);
            w.z = pk_bf16(gx[2 * q + 1].x, gx[2 * q + 1].y);
            w.w = pk_bf16(gx[2 * q + 1].z, gx[2 * q + 1].w);
            *(uint4*)(base + woff[q]) = w;
        }
    };

    // ---- B fragment bases (frag idx = kstep*16 + wc*4 + n; 512 ushorts/frag)
    const unsigned short* bhp = Bhi + ((size_t)(wc * 4) * 64 + lane) * 8;
    const unsigned short* blp = Blo + ((size_t)(wc * 4) * 64 + lane) * 8;

    // ---- A fragment addressing
    const int arow_l = lane & 15;
    const int akg    = (lane >> 4) * 16;       // 16-B k-group offset

    f32x4 acc[8][4];
#pragma unroll
    for (int m = 0; m < 8; ++m)
#pragma unroll
        for (int n = 0; n < 4; ++n) acc[m][n] = f32x4{0.f, 0.f, 0.f, 0.f};

    auto body = [&](int t) {
        const char* ab = (const char*)lds_raw + (t & 1) * 32768;
#pragma unroll
        for (int kk = 0; kk < 2; ++kk) {
            // B loads for this k-step (one 32-VGPR set, reused)
            const unsigned short* bhB = bhp + (size_t)(2 * t + kk) * 8192;
            const unsigned short* blB = blp + (size_t)(2 * t + kk) * 8192;
            bf16x8 bh[4], bl[4];
#pragma unroll
            for (int n = 0; n < 4; ++n) {
                bh[n] = *(const bf16x8*)(bhB + n * 512);
                bl[n] = *(const bf16x8*)(blB + n * 512);
            }
            __builtin_amdgcn_s_setprio(1);
#pragma unroll
            for (int mm = 0; mm < 2; ++mm) {
                bf16x8 af[4];
#pragma unroll
                for (int q = 0; q < 4; ++q) {
                    const int arow = wr * 128 + (mm * 4 + q) * 16 + arow_l;
                    af[q] = *(const bf16x8*)(ab + arow * 128 + ((kk * 64 + akg) ^ ((arow & 7) << 4)));
                }
#pragma unroll
                for (int n = 0; n < 4; ++n)
#pragma unroll
                    for (int q = 0; q < 4; ++q)
                        acc[mm * 4 + q][n] = __builtin_amdgcn_mfma_f32_16x16x32_bf16(af[q], bh[n], acc[mm * 4 + q][n], 0, 0, 0);
#pragma unroll
                for (int n = 0; n < 4; ++n)
#pragma unroll
                    for (int q = 0; q < 4; ++q)
                        acc[mm * 4 + q][n] = __builtin_amdgcn_mfma_f32_16x16x32_bf16(af[q], bl[n], acc[mm * 4 + q][n], 0, 0, 0);
            }
            __builtin_amdgcn_s_setprio(0);
        }
        // stage x(t+1) (regs loaded at end of iter t-1, ~5000 cyc ago),
        // then refill gx with x(t+2); barrier keeps only LDS ordering.
        if (t < NT - 1) {
            dswrite((t + 1) & 1);
            if (t + 2 < NT) issueX(t + 2);
            BARRIER_LGKM();
        }
    };

    // prologue: x(0) -> LDS buf0; x(1) -> gx (in flight across barrier)
    issueX(0);
    dswrite(0);
    issueX(1);
    BARRIER_LGKM();

    for (int t = 0; t < NT; ++t) body(t);

    // =========== epilogue: SiLU in-register, logits, flash-pool ===========
    float* a_red  = (float*)lds_raw;            // [4][256]  4 KB
    float* a_vals = (float*)(lds_raw + 4096);   // [256]     1 KB
    float* redm   = (float*)(lds_raw + 5120);   // [8]
    float* bc2    = (float*)(lds_raw + 5152);   // [2]
    float* pp     = (float*)(lds_raw + 5248);   // [2][256]  2 KB

    const int rg = lane >> 4;
    float bpc[4], wac[4];
#pragma unroll
    for (int n = 0; n < 4; ++n) {
        int col = wc * 64 + n * 16 + (lane & 15);
        bpc[n] = bp[col];
        wac[n] = Wa[col];
    }

    // SiLU (overwrite acc with h, fp32) + per-row attention-logit partials
    float pa[32];
#pragma unroll
    for (int i = 0; i < 32; ++i) pa[i] = 0.f;
#pragma unroll
    for (int m = 0; m < 8; ++m)
#pragma unroll
        for (int n = 0; n < 4; ++n)
#pragma unroll
            for (int j = 0; j < 4; ++j) {
                float v  = acc[m][n][j] + bpc[n];
                float hh = v / (1.f + __expf(-v));
                acc[m][n][j] = hh;
                pa[m * 4 + j] = fmaf(hh, wac[n], pa[m * 4 + j]);
            }
    // reduce pa over the 16 lanes sharing each row
#pragma unroll
    for (int i = 0; i < 32; ++i) {
#pragma unroll
        for (int off = 1; off < 16; off <<= 1)
            pa[i] += __shfl_xor(pa[i], off, 64);
    }
    __syncthreads();          // K-loop LDS reads done before overlay writes
    if ((lane & 15) == 0) {
#pragma unroll
        for (int m = 0; m < 8; ++m)
#pragma unroll
            for (int j = 0; j < 4; ++j)
                a_red[wc * BM + wr * 128 + m * 16 + rg * 4 + j] = pa[m * 4 + j];
    }
    __syncthreads();
    if (tid < BM) {
        float av = a_red[tid] + a_red[BM + tid] + a_red[2 * BM + tid] + a_red[3 * BM + tid] + ba[0];
        a_vals[tid] = (lrow0 + tid < len) ? av : -3e38f;   // mask invalid rows
    }
    __syncthreads();

    // m_t = max over valid rows
    float mv = (tid < BM) ? a_vals[tid] : -3e38f;
    mv = wave_reduce_max(mv);
    if (lane == 0) redm[wave] = mv;
    __syncthreads();
    if (tid == 0) {
        float m = redm[0];
#pragma unroll
        for (int w = 1; w < 8; ++w) m = fmaxf(m, redm[w]);
        bc2[0] = m;
    }
    __syncthreads();
    const float m_t = bc2[0];

    // l_t = sum exp(a - m_t) over valid rows
    float es = (tid < BM) ? __expf(a_vals[tid] - m_t) : 0.f;
    es = wave_reduce_sum(es);
    if (lane == 0) redm[wave] = es;
    __syncthreads();
    float l_t = 0.f;
    if (tid == 0) {
#pragma unroll
        for (int w = 0; w < 8; ++w) l_t += redm[w];
    }

    // pooled partial: pp[c] = sum_rows exp(a-m_t) * h[row][c]  (h fp32 in acc)
    float ev[32];
    const int rbase = wr * 128 + rg * 4;
#pragma unroll
    for (int m = 0; m < 8; ++m)
#pragma unroll
        for (int j = 0; j < 4; ++j)
            ev[m * 4 + j] = __expf(a_vals[rbase + m * 16 + j] - m_t);
#pragma unroll
    for (int n = 0; n < 4; ++n) {
        float s = 0.f;
#pragma unroll
        for (int m = 0; m < 8; ++m)
#pragma unroll
            for (int j = 0; j < 4; ++j)
                s = fmaf(ev[m * 4 + j], acc[m][n][j], s);
        s += __shfl_xor(s, 16, 64);
        s += __shfl_xor(s, 32, 64);
        if (lane < 16) pp[wr * 256 + wc * 64 + n * 16 + lane] = s;
    }
    __syncthreads();

    const size_t pbase = ((size_t)bag * 32 + (blk & 31)) * PSTRIDE;
    if (tid < BM) part[pbase + tid] = pp[tid] + pp[256 + tid];
    if (tid == 0) { part[pbase + 256] = m_t; part[pbase + 257] = l_t; }
}

// ---------------------------------------------------------------------------
// final: one block per bag. Flash-combine the per-tile partials, then
// logits = pooled @ Wc + bc.
// ---------------------------------------------------------------------------
__global__ __launch_bounds__(256)
void final_kernel(const float* __restrict__ part, const int* __restrict__ lengths,
                  const float* __restrict__ Wc, const float* __restrict__ bc,
                  float* __restrict__ out)
{
    __shared__ float red0[4], red1[4];
    const int b = blockIdx.x;
    const int c = threadIdx.x;
    const int len = lengths[b];
    int nt = (len + BM - 1) / BM;
    if (nt > 32) nt = 32;

    float mg = -3e38f;
    for (int t = 0; t < nt; ++t)
        mg = fmaxf(mg, part[((size_t)b * 32 + t) * PSTRIDE + 256]);

    float W = 0.f, pooled = 0.f;
    for (int t = 0; t < nt; ++t) {
        const size_t pb = ((size_t)b * 32 + t) * PSTRIDE;
        float sc = __expf(part[pb + 256] - mg);
        W      = fmaf(sc, part[pb + 257], W);
        pooled = fmaf(sc, part[pb + c],  pooled);
    }
    pooled /= W;

    const float wc0 = Wc[c * NC + 0], wc1 = Wc[c * NC + 1];
    const int wave = threadIdx.x >> 6, lane = threadIdx.x & 63;
    float l0 = wave_reduce_sum(pooled * wc0);
    float l1 = wave_reduce_sum(pooled * wc1);
    if (lane == 0) { red0[wave] = l0; red1[wave] = l1; }
    __syncthreads();
    if (threadIdx.x == 0) {
        out[b * NC + 0] = red0[0] + red0[1] + red0[2] + red0[3] + bc[0];
        out[b * NC + 1] = red1[0] + red1[1] + red1[2] + red1[3] + bc[1];
    }
}

extern "C" void kernel_launch(void* const* d_in, const int* in_sizes, int n_in,
                              void* d_out, int out_size, void* d_ws, size_t ws_size,
                              hipStream_t stream)
{
    const float* x       = (const float*)d_in[0];
    const int*   lengths = (const int*)d_in[1];
    const float* Wp      = (const float*)d_in[2];
    const float* bp      = (const float*)d_in[3];
    const float* Wa      = (const float*)d_in[4];
    const float* ba      = (const float*)d_in[5];
    const float* Wc      = (const float*)d_in[6];
    const float* bc      = (const float*)d_in[7];
    float* out = (float*)d_out;

    // workspace layout
    unsigned short* whi = (unsigned short*)d_ws;              // 512 KB
    unsigned short* wlo = whi + 262144;                       // 512 KB
    float* part = (float*)(wlo + 262144);                     // 8*32*260 f = 260 KB

    pack_kernel<<<128, 256, 0, stream>>>(Wp, whi, wlo);
    gemm_kernel<<<M_ALL / BM, 512, 0, stream>>>(x, whi, wlo, bp, Wa, ba, lengths, part);
    final_kernel<<<NB, 256, 0, stream>>>(part, lengths, Wc, bc, out);
}